// Round 2
// baseline (216.709 us; speedup 1.0000x reference)
//
#include <hip/hip_runtime.h>
#include <cmath>

// ---------------------------------------------------------------------------
// Problem constants (from reference)
// ---------------------------------------------------------------------------
constexpr int kNsh    = 9;      // (LMAX+1)^2, LMAX=2
constexpr int kF      = 64;
constexpr int kNrbf   = 20;
constexpr int kNAtoms = 1000;
constexpr int kNPairs = 10000;
constexpr float kCutoffF = 5.0f;
constexpr int kMaxNZ  = 200;

// ---------------------------------------------------------------------------
// Compile-time real Clebsch-Gordan table (mirrors the reference _real_cg)
// ---------------------------------------------------------------------------
struct CGSparse {
  int n;
  int c[kMaxNZ];
  int a[kMaxNZ];
  int b[kMaxNZ];
  float v[kMaxNZ];
};

constexpr double cfact(int n) {
  double r = 1.0;
  for (int i = 2; i <= n; i++) r *= (double)i;
  return r;
}
constexpr double cabs_(double x) { return x < 0 ? -x : x; }
constexpr double csqrt_(double x) {
  if (x <= 0.0) return 0.0;
  double g = x < 1.0 ? 1.0 : x;
  for (int i = 0; i < 60; i++) g = 0.5 * (g + x / g);
  return g;
}

constexpr double cg_cplx(int l1, int m1, int l2, int m2, int l3, int m3) {
  if (m3 != m1 + m2) return 0.0;
  int lo = l1 > l2 ? l1 - l2 : l2 - l1;
  if (l3 < lo || l3 > l1 + l2) return 0.0;
  double pre = csqrt_((2 * l3 + 1) * cfact(l3 + l1 - l2) * cfact(l3 - l1 + l2) *
                      cfact(l1 + l2 - l3) / cfact(l1 + l2 + l3 + 1));
  pre *= csqrt_(cfact(l3 + m3) * cfact(l3 - m3) * cfact(l1 - m1) *
                cfact(l1 + m1) * cfact(l2 - m2) * cfact(l2 + m2));
  double s = 0.0;
  for (int k = 0; k <= l1 + l2 - l3; k++) {
    int d0 = k, d1 = l1 + l2 - l3 - k, d2 = l1 - m1 - k;
    int d3 = l2 + m2 - k, d4 = l3 - l2 + m1 + k, d5 = l3 - l1 - m2 + k;
    if (d0 < 0 || d1 < 0 || d2 < 0 || d3 < 0 || d4 < 0 || d5 < 0) continue;
    double den = cfact(d0) * cfact(d1) * cfact(d2) * cfact(d3) * cfact(d4) * cfact(d5);
    s += ((k % 2) ? -1.0 : 1.0) / den;
  }
  return pre * s;
}

constexpr CGSparse build_cg() {
  CGSparse out{};
  int lidx[9] = {0, 1, 1, 1, 2, 2, 2, 2, 2};
  int midx[9] = {0, -1, 0, 1, -2, -1, 0, 1, 2};
  double Ur[9][9] = {};
  double Ui[9][9] = {};
  for (int l = 0; l <= 2; l++) {
    int base = l * l + l;
    Ur[base][base] = 1.0;
    for (int m = 1; m <= l; m++) {
      double s2 = 1.0 / csqrt_(2.0);
      double sgn = (m % 2) ? -1.0 : 1.0;
      Ur[base + m][base - m] = s2;
      Ur[base + m][base + m] = sgn * s2;
      Ui[base - m][base - m] = s2;
      Ui[base - m][base + m] = -sgn * s2;
    }
  }
  double cgr[9][9][9] = {};
  for (int i = 0; i < 9; i++)
    for (int j = 0; j < 9; j++)
      for (int k = 0; k < 9; k++) {
        double cv = cg_cplx(lidx[i], midx[i], lidx[j], midx[j], lidx[k], midx[k]);
        if (cv == 0.0) continue;
        for (int a2 = 0; a2 < 9; a2++) {
          if (Ur[a2][i] == 0.0 && Ui[a2][i] == 0.0) continue;
          for (int b2 = 0; b2 < 9; b2++) {
            if (Ur[b2][j] == 0.0 && Ui[b2][j] == 0.0) continue;
            for (int c2 = 0; c2 < 9; c2++) {
              if (Ur[c2][k] == 0.0 && Ui[c2][k] == 0.0) continue;
              double ar = Ur[a2][i], ai = Ui[a2][i];
              double br = Ur[b2][j], bi = Ui[b2][j];
              double cr = Ur[c2][k], ci = -Ui[c2][k];  // conj
              double pr = ar * br - ai * bi;
              double pi = ar * bi + ai * br;
              double rr = pr * cr - pi * ci;  // real part
              cgr[c2][a2][b2] += rr * cv;
            }
          }
        }
      }
  int n = 0;
  for (int c2 = 0; c2 < 9; c2++)
    for (int a2 = 0; a2 < 9; a2++)
      for (int b2 = 0; b2 < 9; b2++) {
        bool mask = ((lidx[a2] + lidx[b2]) % 2) == (lidx[c2] % 2);
        double v = mask ? cgr[c2][a2][b2] : 0.0;
        if (cabs_(v) > 1e-9) {
          out.c[n] = c2;
          out.a[n] = a2;
          out.b[n] = b2;
          out.v[n] = (float)v;
          n++;
        }
      }
  out.n = n;
  return out;
}

constexpr CGSparse CG = build_cg();
static_assert(CG.n > 0 && CG.n <= kMaxNZ, "CG table size out of range");

// ---------------------------------------------------------------------------
// ws layout (floats)
// ---------------------------------------------------------------------------
// x0      : 576000
// x1      : 576000
// Ypd     : 10000*16
// Wpair   : 2*10000*192
// seg     : 1001 ints

// ---------------------------------------------------------------------------
// Pre-kernels
// ---------------------------------------------------------------------------

__global__ void k_init_x(const int* __restrict__ Z, const float* __restrict__ emb,
                         float* __restrict__ x) {
  int tid = blockIdx.x * blockDim.x + threadIdx.x;
  if (tid >= kNAtoms * kNsh * kF) return;
  int f = tid & 63;
  int c = (tid >> 6) % kNsh;
  int atom = tid / (kNsh * kF);
  float v = 0.0f;
  if (c == 0) v = emb[Z[atom] * kF + f];
  x[tid] = v;
}

// seg[a] = lower_bound(idx_i, a) for a in [0, 1000]
__global__ void k_seg(const int* __restrict__ idx_i, int* __restrict__ seg) {
  int a = blockIdx.x * blockDim.x + threadIdx.x;
  if (a > kNAtoms) return;
  int lo = 0, hi = kNPairs;
  while (lo < hi) {
    int mid = (lo + hi) >> 1;
    if (idx_i[mid] < a) lo = mid + 1; else hi = mid;
  }
  seg[a] = lo;
}

// Per-pair: Y[9] -> Ypd[p*16+..]; W[t][l][f] = (radial@Wf + bf)*cut -> Wpair
// One wave per pair, 4 waves/block.
__global__ __launch_bounds__(256) void k_pre_pairs(
    const float* __restrict__ rij, const float* __restrict__ Wf,
    const float* __restrict__ bf, float* __restrict__ Ypd,
    float* __restrict__ Wpair) {
  int wv = threadIdx.x >> 6;
  int f = threadIdx.x & 63;
  int p = blockIdx.x * 4 + wv;
  if (p >= kNPairs) return;
  float rx = rij[3 * p + 0], ry = rij[3 * p + 1], rz = rij[3 * p + 2];
  float d = sqrtf(rx * rx + ry * ry + rz * rz);
  float inv = 1.0f / d;
  float x = rx * inv, y = ry * inv, z = rz * inv;
  const float c0 = 0.28209479177387814f;  // 0.5/sqrt(pi)
  const float c1 = 0.4886025119029199f;   // sqrt(3/(4pi))
  const float c2 = 1.0925484305920792f;   // 0.5*sqrt(15/pi)
  const float c3 = 0.31539156525252005f;  // 0.25*sqrt(5/pi)
  const float c4 = 0.5462742152960396f;   // 0.25*sqrt(15/pi)
  if (f < 9) {
    float yv =
        (f == 0) ? c0 :
        (f == 1) ? c1 * y :
        (f == 2) ? c1 * z :
        (f == 3) ? c1 * x :
        (f == 4) ? c2 * x * y :
        (f == 5) ? c2 * y * z :
        (f == 6) ? c3 * (3.0f * z * z - 1.0f) :
        (f == 7) ? c2 * x * z :
                   c4 * (x * x - y * y);
    Ypd[p * 16 + f] = yv;
  }
  float cut = (d < kCutoffF) ? 0.5f * (cosf(d * (float)(M_PI / 5.0)) + 1.0f) : 0.0f;
  // radial (wave-uniform)
  float radial[kNrbf];
  const float width = kCutoffF / (kNrbf - 1);
  const float coef = -0.5f / (width * width);
  #pragma unroll
  for (int k = 0; k < kNrbf; k++) {
    float off = (kCutoffF * k) / (kNrbf - 1);
    float t = d - off;
    radial[k] = expf(coef * t * t);
  }
  #pragma unroll
  for (int t = 0; t < 2; t++) {
    #pragma unroll
    for (int l = 0; l < 3; l++) {
      float w = bf[t * 192 + l * 64 + f];
      #pragma unroll
      for (int k = 0; k < kNrbf; k++) {
        w += radial[k] * Wf[t * (kNrbf * 192) + k * 192 + l * 64 + f];
      }
      Wpair[t * (kNPairs * 192) + p * 192 + l * 64 + f] = w * cut;
    }
  }
}

// ---------------------------------------------------------------------------
// Fused per-interaction kernel: 1 block (128 thr = 2 waves) per atom.
//   message segment-sum -> dx ; ddx = dx@W1 ; t2 = dx + CG(dx,ddx) ;
//   dx2 = t2@W2 ; gate ; dx3 = dx2*sig(gate) ; x_out = x_in + dx3@W3
// ---------------------------------------------------------------------------
__global__ __launch_bounds__(128) void k_fused(
    const float* __restrict__ x_in, const int* __restrict__ idx_j,
    const int* __restrict__ seg, const float* __restrict__ Ypd,
    const float* __restrict__ Wpair,  // [p][3][64] for this t
    const float* __restrict__ W1, const float* __restrict__ W2,
    const float* __restrict__ W3, const float* __restrict__ Wg,
    const float* __restrict__ bg, float* __restrict__ x_out) {
  const int atom = blockIdx.x;
  const int wv = threadIdx.x >> 6;  // 0 or 1
  const int f = threadIdx.x & 63;

  __shared__ float sA[kF][12];        // f-major staging (pad 12) for broadcasts
  __shared__ float sB[2][kNsh][kF];   // c-major staging / wave partials
  float (*sD)[kF] = sB[0];            // ddx / reuse
  float (*sE)[kF] = sB[1];            // dx2 / reuse

  // ---------------- message phase ----------------
  float y[9] = {0, 0, 0, 0, 0, 0, 0, 0, 0};
  const int s0 = seg[atom], s1 = seg[atom + 1];
  for (int p0 = s0 + wv; p0 < s1; p0 += 2) {
    const int p = __builtin_amdgcn_readfirstlane(p0);
    const float* Yp = Ypd + p * 16;
    const float* Wp = Wpair + p * 192;
    float Wl0 = Wp[f], Wl1 = Wp[64 + f], Wl2 = Wp[128 + f];
    const int j = __builtin_amdgcn_readfirstlane(idx_j[p]);
    const float* xj = x_in + j * (kNsh * kF);
    float xv[9];
    #pragma unroll
    for (int a = 0; a < 9; a++) xv[a] = xj[a * kF + f];
    float YW[9];
    YW[0] = Yp[0] * Wl0;
    YW[1] = Yp[1] * Wl1;
    YW[2] = Yp[2] * Wl1;
    YW[3] = Yp[3] * Wl1;
    #pragma unroll
    for (int b = 4; b < 9; b++) YW[b] = Yp[b] * Wl2;
    #pragma unroll
    for (int e = 0; e < CG.n; e++) {
      y[CG.c[e]] += CG.v[e] * YW[CG.b[e]] * xv[CG.a[e]];
    }
  }
  #pragma unroll
  for (int c = 0; c < 9; c++) sB[wv][c][f] = y[c];
  __syncthreads();  // 1
  float dxv[9];
  #pragma unroll
  for (int c = 0; c < 9; c++) dxv[c] = sB[0][c][f] + sB[1][c][f];
  if (wv == 0) {
    #pragma unroll
    for (int c = 0; c < 9; c++) sA[f][c] = dxv[c];
  }
  __syncthreads();  // 2

  const int c_base = wv * 4;
  const int c_cnt = 4 + wv;  // wave0: c 0..3, wave1: c 4..8

  // ---------------- matmul1: ddx = dx @ W1 (c-split) ----------------
  float acc[5] = {0, 0, 0, 0, 0};
  for (int k = 0; k < kF; k++) {
    float w = W1[k * kF + f];
    #pragma unroll
    for (int i = 0; i < 5; i++) {
      if (i < c_cnt) acc[i] += sA[k][c_base + i] * w;
    }
  }
  #pragma unroll
  for (int i = 0; i < 5; i++) {
    if (i < c_cnt) sD[c_base + i][f] = acc[i];
  }
  __syncthreads();  // 3

  // ---------------- tp + t2 (every lane, full 9) ----------------
  float ddx[9];
  #pragma unroll
  for (int c = 0; c < 9; c++) ddx[c] = sD[c][f];
  float t2[9];
  #pragma unroll
  for (int c = 0; c < 9; c++) t2[c] = dxv[c];
  #pragma unroll
  for (int e = 0; e < CG.n; e++) {
    t2[CG.c[e]] += CG.v[e] * dxv[CG.a[e]] * ddx[CG.b[e]];
  }
  if (wv == 0) {
    #pragma unroll
    for (int c = 0; c < 9; c++) sA[f][c] = t2[c];
  }
  __syncthreads();  // 4

  // ---------------- matmul2: dx2 = t2 @ W2 (c-split) ----------------
  float acc2[5] = {0, 0, 0, 0, 0};
  for (int k = 0; k < kF; k++) {
    float w = W2[k * kF + f];
    #pragma unroll
    for (int i = 0; i < 5; i++) {
      if (i < c_cnt) acc2[i] += sA[k][c_base + i] * w;
    }
  }
  #pragma unroll
  for (int i = 0; i < 5; i++) {
    if (i < c_cnt) sE[c_base + i][f] = acc2[i];
  }
  __syncthreads();  // 5

  // ---------------- gate (both waves duplicate) ----------------
  float g0 = bg[f], g1 = bg[64 + f], g2 = bg[128 + f];
  for (int k = 0; k < kF; k++) {
    float v0 = sE[0][k];
    g0 += v0 * Wg[k * 192 + f];
    g1 += v0 * Wg[k * 192 + 64 + f];
    g2 += v0 * Wg[k * 192 + 128 + f];
  }
  g0 = 1.0f / (1.0f + expf(-g0));
  g1 = 1.0f / (1.0f + expf(-g1));
  g2 = 1.0f / (1.0f + expf(-g2));
  // dx3 = dx2 * gate[lidx]
  float dx3[9];
  {
    float dx2v[9];
    #pragma unroll
    for (int c = 0; c < 9; c++) dx2v[c] = sE[c][f];
    dx3[0] = dx2v[0] * g0;
    dx3[1] = dx2v[1] * g1;
    dx3[2] = dx2v[2] * g1;
    dx3[3] = dx2v[3] * g1;
    #pragma unroll
    for (int c = 4; c < 9; c++) dx3[c] = dx2v[c] * g2;
  }
  if (wv == 0) {
    #pragma unroll
    for (int c = 0; c < 9; c++) sA[f][c] = dx3[c];
  }
  __syncthreads();  // 6
  // wave1 must also stage: dx3 values identical across waves (both read sE),
  // so single-wave staging above is sufficient.

  // ---------------- matmul3 + output ----------------
  float acc3[5] = {0, 0, 0, 0, 0};
  for (int k = 0; k < kF; k++) {
    float w = W3[k * kF + f];
    #pragma unroll
    for (int i = 0; i < 5; i++) {
      if (i < c_cnt) acc3[i] += sA[k][c_base + i] * w;
    }
  }
  #pragma unroll
  for (int i = 0; i < 5; i++) {
    if (i < c_cnt) {
      int off = atom * (kNsh * kF) + (c_base + i) * kF + f;
      x_out[off] = x_in[off] + acc3[i];
    }
  }
}

// ---------------------------------------------------------------------------
// Launch
// ---------------------------------------------------------------------------
extern "C" void kernel_launch(void* const* d_in, const int* in_sizes, int n_in,
                              void* d_out, int out_size, void* d_ws, size_t ws_size,
                              hipStream_t stream) {
  const int* Z        = (const int*)d_in[0];
  const float* rij    = (const float*)d_in[1];
  const int* idx_i    = (const int*)d_in[2];
  const int* idx_j    = (const int*)d_in[3];
  const float* emb    = (const float*)d_in[4];
  const float* Wf     = (const float*)d_in[5];
  const float* bf     = (const float*)d_in[6];
  const float* W1     = (const float*)d_in[7];
  const float* W2     = (const float*)d_in[8];
  const float* W3     = (const float*)d_in[9];
  const float* Wg     = (const float*)d_in[10];
  const float* bg     = (const float*)d_in[11];
  float* x_final = (float*)d_out;

  float* x0    = (float*)d_ws;                    // 576000
  float* x1    = x0 + kNAtoms * kNsh * kF;        // 576000
  float* Ypd   = x1 + kNAtoms * kNsh * kF;        // 160000
  float* Wpair = Ypd + kNPairs * 16;              // 3,840,000
  int*   seg   = (int*)(Wpair + 2 * kNPairs * 192);  // 1001

  k_init_x<<<(kNAtoms * kNsh * kF + 255) / 256, 256, 0, stream>>>(Z, emb, x0);
  k_pre_pairs<<<(kNPairs + 3) / 4, 256, 0, stream>>>(rij, Wf, bf, Ypd, Wpair);
  k_seg<<<(kNAtoms + 256) / 256, 256, 0, stream>>>(idx_i, seg);

  // t = 0: x0 -> x1 ; t = 1: x1 -> d_out
  k_fused<<<kNAtoms, 128, 0, stream>>>(
      x0, idx_j, seg, Ypd, Wpair, W1, W2, W3, Wg, bg, x1);
  k_fused<<<kNAtoms, 128, 0, stream>>>(
      x1, idx_j, seg, Ypd, Wpair + kNPairs * 192,
      W1 + kF * kF, W2 + kF * kF, W3 + kF * kF,
      Wg + kF * 192, bg + 192, x_final);
}